// Round 7
// baseline (156.142 us; speedup 1.0000x reference)
//
#include <hip/hip_runtime.h>

#define B_ 2
#define S_ 2048
#define D_ 1024
#define H_ 16
#define DH 64
#define KB 64
#define SCALE_LOG2 0.18033688011112042f   // (1/sqrt(64)) * log2(e)
#define THR 11.0f                          // defer-max threshold (log2 domain), P <= 2^11 fits f16

typedef _Float16 f16x8 __attribute__((ext_vector_type(8)));
typedef _Float16 f16x4 __attribute__((ext_vector_type(4)));
typedef float f32x4 __attribute__((ext_vector_type(4)));

// Swapped-QK layout (verified r4, passed):
//  QK: D = mfma_16x16x32(A=K, B=Q): lane(n,g) -> P^T[key=16t+4g+r][q=qrow+n]
//  PV: D = mfma_16x16x16(A=P, B=V): A k=4g+j == lane's own sc -> no shuffle
//  V^T LDS: (dh,key) at halfs dh*64 + ((key>>3 ^ (dh&7))<<3) + (key&7); b128 write / b64 read at bank floor

__global__ __launch_bounds__(256, 2) void mha_fwd(
    const float* __restrict__ qg, const float* __restrict__ kg,
    const float* __restrict__ vg, float* __restrict__ out)
{
  __shared__ __align__(16) _Float16 lds_k[2][KB * DH];   // 2 x 8KB
  __shared__ __align__(16) _Float16 lds_v[2][DH * KB];   // 2 x 8KB

  // 512 blocks: XCD-bijective swizzle, bh-major chunks
  int bx = blockIdx.x;
  int L  = (bx & 7) * 64 + (bx >> 3);
  int bh  = L >> 4;
  int qbp = L & 15;
  int h = bh & 15;
  int b = bh >> 4;

  int tid  = threadIdx.x;
  int wid  = tid >> 6;
  int lane = tid & 63;
  int n    = lane & 15;
  int g    = lane >> 4;

  const float* qbase = qg + (size_t)b * S_ * D_ + h * DH;
  const float* kbase = kg + (size_t)b * S_ * D_ + h * DH;
  const float* vbase = vg + (size_t)b * S_ * D_ + h * DH;

  const int skey  = tid >> 2;   // K staging: one key row / thread
  const int spart = tid & 3;    // K staging: dh 16-chunk
  const int vdh   = tid & 63;   // V staging: one dh column / thread
  const int vkq   = tid >> 6;   // V staging: key quarter

  float4 kf[4];
  float  vf[16];

  auto load_tile = [&](int kt) {
    const float* kp = kbase + (size_t)(kt * KB + skey) * D_ + spart * 16;
#pragma unroll
    for (int i = 0; i < 4; ++i) kf[i] = ((const float4*)kp)[i];
    const float* vp = vbase + (size_t)(kt * KB + vkq * 16) * D_ + vdh;
#pragma unroll
    for (int j = 0; j < 16; ++j) vf[j] = vp[(size_t)j * D_];
  };

  auto store_tile = [&](int buf) {
    const float* kfl = (const float*)kf;
    f16x8 h0, h1;
#pragma unroll
    for (int j = 0; j < 8; ++j) { h0[j] = (_Float16)kfl[j]; h1[j] = (_Float16)kfl[8 + j]; }
    int c0 = spart * 2;
    char* kb_ = (char*)&lds_k[buf][0];
    *(f16x8*)(kb_ + skey * 128 + (((c0    ) ^ (skey & 7)) << 4)) = h0;
    *(f16x8*)(kb_ + skey * 128 + (((c0 + 1) ^ (skey & 7)) << 4)) = h1;
    f16x8 v0, v1;
#pragma unroll
    for (int j = 0; j < 8; ++j) { v0[j] = (_Float16)vf[j]; v1[j] = (_Float16)vf[8 + j]; }
    int kb8 = vkq * 2;
    _Float16* vt = &lds_v[buf][0] + vdh * 64;
    *(f16x8*)(vt + (((kb8    ) ^ (vdh & 7)) << 3)) = v0;
    *(f16x8*)(vt + (((kb8 + 1) ^ (vdh & 7)) << 3)) = v1;
  };

  for (int ph = 0; ph < 2; ++ph) {
    const int qb   = ph ? (31 - qbp) : qbp;   // paired: 33 tiles / block total
    const int nkt  = qb + 1;
    const int qrow = qb * 64 + wid * 16;

    // ---- Q B-fragments (scale*log2e folded) ----
    f16x8 bq[2];
    {
      const float* qp = qbase + (size_t)(qrow + n) * D_ + g * 8;
#pragma unroll
      for (int c = 0; c < 2; ++c) {
        float4 x0 = *(const float4*)(qp + c * 32);
        float4 x1 = *(const float4*)(qp + c * 32 + 4);
        f16x8 a;
        a[0]=(_Float16)(x0.x*SCALE_LOG2); a[1]=(_Float16)(x0.y*SCALE_LOG2);
        a[2]=(_Float16)(x0.z*SCALE_LOG2); a[3]=(_Float16)(x0.w*SCALE_LOG2);
        a[4]=(_Float16)(x1.x*SCALE_LOG2); a[5]=(_Float16)(x1.y*SCALE_LOG2);
        a[6]=(_Float16)(x1.z*SCALE_LOG2); a[7]=(_Float16)(x1.w*SCALE_LOG2);
        bq[c] = a;
      }
    }

    f32x4 o_acc[4] = {};
    float m_run = 0.f, l_run = 0.f;   // m starts at 0: speculative exp2 never sees +inf

    load_tile(0);
    store_tile(0);
    __syncthreads();
    int cur = 0;

    for (int kt = 0; kt < nkt; ++kt) {
      if (kt + 1 < nkt) load_tile(kt + 1);      // issue early; latency hides under compute

      __builtin_amdgcn_s_setprio(1);
      // ---- QK^T from buf[cur] ----
      const char* kb_ = (const char*)&lds_k[cur][0];
      f32x4 sc[4] = {};
#pragma unroll
      for (int t = 0; t < 4; ++t) {
        int keyl = t * 16 + n;
#pragma unroll
        for (int c = 0; c < 2; ++c) {
          int off = keyl * 128 + (((c * 4 + g) ^ (keyl & 7)) << 4);
          f16x8 ak = *(f16x8*)(kb_ + off);
          sc[t] = __builtin_amdgcn_mfma_f32_16x16x32_f16(ak, bq[c], sc[t], 0, 0, 0);
        }
      }

      // ---- causal mask: last tile only ----
      if (kt == nkt - 1) {
        int q = qrow + n;
#pragma unroll
        for (int t = 0; t < 4; ++t)
#pragma unroll
          for (int r = 0; r < 4; ++r) {
            int key = kt * KB + t * 16 + 4 * g + r;
            if (key > q) sc[t][r] = -1e30f;
          }
      }

      // ---- speculative softmax (defer-max): p first, row-max check in parallel ----
      float mxt[4];
#pragma unroll
      for (int t = 0; t < 4; ++t)
        mxt[t] = fmaxf(fmaxf(sc[t][0], sc[t][1]), fmaxf(sc[t][2], sc[t][3]));
      float mx = fmaxf(fmaxf(mxt[0], mxt[1]), fmaxf(mxt[2], mxt[3]));
      mx = fmaxf(mx, __shfl_xor(mx, 16, 64));
      mx = fmaxf(mx, __shfl_xor(mx, 32, 64));   // full 64-key row max (independent of exps below)

      float s = 0.f;
#pragma unroll
      for (int t = 0; t < 4; ++t) {
        f32x4 p = sc[t];
#pragma unroll
        for (int r = 0; r < 4; ++r) p[r] = exp2f(p[r] - m_run);
        sc[t] = p;
        s += (p[0] + p[1]) + (p[2] + p[3]);
      }

      if (!__all(mx <= m_run + THR)) {          // rare rescale path
        float mnew  = fmaxf(m_run, mx);
        float alpha = exp2f(m_run - mnew);      // per-lane (row q=n)
#pragma unroll
        for (int t = 0; t < 4; ++t)
#pragma unroll
          for (int r = 0; r < 4; ++r) sc[t][r] *= alpha;
        s *= alpha;
        l_run *= alpha;
        m_run = mnew;
        float ar[4];                            // alpha of o_acc rows 4g+r
#pragma unroll
        for (int r = 0; r < 4; ++r) ar[r] = __shfl(alpha, 4 * g + r, 64);
#pragma unroll
        for (int nt = 0; nt < 4; ++nt)
#pragma unroll
          for (int r = 0; r < 4; ++r) o_acc[nt][r] *= ar[r];
      }
      l_run += s;

      // ---- P fragments (lane-local) ----
      f16x4 pa[4];
#pragma unroll
      for (int u = 0; u < 4; ++u) {
        f16x4 p4;
#pragma unroll
        for (int r = 0; r < 4; ++r) p4[r] = (_Float16)sc[u][r];
        pa[u] = p4;
      }

      // ---- PV from buf[cur] ----
      const _Float16* vb_ = &lds_v[cur][0];
#pragma unroll
      for (int u = 0; u < 4; ++u) {
#pragma unroll
        for (int nt = 0; nt < 4; ++nt) {
          int dhv = nt * 16 + n;
          int off = dhv * 64 + ((((2 * u + (g >> 1)) ^ (n & 7))) << 3) + ((g & 1) << 2);
          f16x4 bv = *(f16x4*)(vb_ + off);
          o_acc[nt] = __builtin_amdgcn_mfma_f32_16x16x16f16(pa[u], bv, o_acc[nt], 0, 0, 0);
        }
      }
      __builtin_amdgcn_s_setprio(0);

      // ---- T14 write-late: stage kt+1 into the other buffer, single barrier ----
      if (kt + 1 < nkt) store_tile(cur ^ 1);
      __syncthreads();
      cur ^= 1;
    } // kt

    // ---- epilogue ----
    float lsum = l_run;
    lsum += __shfl_xor(lsum, 16, 64);
    lsum += __shfl_xor(lsum, 32, 64);
    float linv[4];
#pragma unroll
    for (int r = 0; r < 4; ++r) linv[r] = 1.0f / __shfl(lsum, 4 * g + r, 64);

    float* ob = out + ((size_t)b * S_ + qrow) * D_ + h * DH;
#pragma unroll
    for (int r = 0; r < 4; ++r) {
      float* op = ob + (size_t)(4 * g + r) * D_ + n;
#pragma unroll
      for (int nt = 0; nt < 4; ++nt)
        op[nt * 16] = o_acc[nt][r] * linv[r];
    }
  } // ph
}

extern "C" void kernel_launch(void* const* d_in, const int* in_sizes, int n_in,
                              void* d_out, int out_size, void* d_ws, size_t ws_size,
                              hipStream_t stream) {
  const float* q = (const float*)d_in[0];
  const float* k = (const float*)d_in[1];
  const float* v = (const float*)d_in[2];
  // d_in[3]: causal mask (tril by construction) — handled analytically.
  float* out = (float*)d_out;
  dim3 grid(512);
  mha_fwd<<<grid, 256, 0, stream>>>(q, k, v, out);
}

// Round 10
// 154.445 us; speedup vs baseline: 1.0110x; 1.0110x over previous
//
#include <hip/hip_runtime.h>

#define B_ 2
#define S_ 2048
#define D_ 1024
#define H_ 16
#define DH 64
#define KB 64
#define SCALE_LOG2 0.18033688011112042f   // (1/sqrt(64)) * log2(e)
#define THR 11.0f                          // defer-max threshold (log2 domain); P <= 2^11 fits f16

typedef _Float16 f16x8 __attribute__((ext_vector_type(8)));
typedef _Float16 f16x4 __attribute__((ext_vector_type(4)));
typedef __fp16   h16x2 __attribute__((ext_vector_type(2)));   // cvt_pkrtz result type
typedef float f32x4 __attribute__((ext_vector_type(4)));

// Swapped-QK layout (verified r4/r7, passed):
//  QK: D = mfma_16x16x32(A=K, B=Q): lane(n,g) -> P^T[key=16t+4g+r][q=qrow+n]
//  PV: D = mfma_16x16x16(A=P, B=V): A k=4g+j == lane's own sc -> no shuffle
//  V^T LDS: (dh,key) at halfs dh*64 + ((key>>3 ^ (dh&7))<<3) + (key&7)

__device__ __forceinline__ f16x8 cvt8(const float* x, float s) {
  f16x8 r;
#pragma unroll
  for (int i = 0; i < 4; ++i) {
    h16x2 p = __builtin_amdgcn_cvt_pkrtz(x[2*i] * s, x[2*i+1] * s);
    r[2*i] = (_Float16)p[0]; r[2*i+1] = (_Float16)p[1];
  }
  return r;
}

__global__ __launch_bounds__(256) void mha_fwd(
    const float* __restrict__ qg, const float* __restrict__ kg,
    const float* __restrict__ vg, float* __restrict__ out)
{
  __shared__ __align__(16) _Float16 lds_k[KB * DH];   // 8KB
  __shared__ __align__(16) _Float16 lds_v[DH * KB];   // 8KB

  // grid 1024 -> (xcd, qb descending, bh chunk-of-4 per XCD):
  //  - bijective: bx <-> (xcd, L&3 -> bh, L>>2 -> qb)
  //  - qb=31 blocks dispatch first (LPT balance)
  //  - an XCD's consecutive blocks share (b,h) -> K/V L2-resident (4MB/XCD)
  int bx  = blockIdx.x;
  int xcd = bx & 7;
  int L   = bx >> 3;            // 0..127
  int bh  = xcd * 4 + (L & 3);  // 0..31
  int qb  = 31 - (L >> 2);      // 0..31, descending with dispatch order
  int h = bh & 15;
  int b = bh >> 4;

  int tid  = threadIdx.x;
  int wid  = tid >> 6;
  int lane = tid & 63;
  int n    = lane & 15;
  int g    = lane >> 4;

  const float* qbase = qg + (size_t)b * S_ * D_ + h * DH;
  const float* kbase = kg + (size_t)b * S_ * D_ + h * DH;
  const float* vbase = vg + (size_t)b * S_ * D_ + h * DH;

  const int skey  = tid >> 2;   // K staging: one key row / thread
  const int spart = tid & 3;    // K staging: dh 16-chunk
  const int vdh   = tid & 63;   // V staging: one dh column / thread
  const int vkq   = tid >> 6;   // V staging: key quarter

  float4 kf[4];
  float  vf[16];

  auto load_tile = [&](int kt) {
    const float* kp = kbase + (size_t)(kt * KB + skey) * D_ + spart * 16;
#pragma unroll
    for (int i = 0; i < 4; ++i) kf[i] = ((const float4*)kp)[i];
    const float* vp = vbase + (size_t)(kt * KB + vkq * 16) * D_ + vdh;
#pragma unroll
    for (int j = 0; j < 16; ++j) vf[j] = vp[(size_t)j * D_];
  };

  auto store_tile = [&]() {
    const float* kfl = (const float*)kf;
    f16x8 h0 = cvt8(kfl, 1.f), h1 = cvt8(kfl + 8, 1.f);
    int c0 = spart * 2;
    char* kb_ = (char*)lds_k;
    *(f16x8*)(kb_ + skey * 128 + (((c0    ) ^ (skey & 7)) << 4)) = h0;
    *(f16x8*)(kb_ + skey * 128 + (((c0 + 1) ^ (skey & 7)) << 4)) = h1;
    f16x8 v0 = cvt8(vf, 1.f), v1 = cvt8(vf + 8, 1.f);
    int kb8 = vkq * 2;
    _Float16* vt = lds_v + vdh * 64;
    *(f16x8*)(vt + (((kb8    ) ^ (vdh & 7)) << 3)) = v0;
    *(f16x8*)(vt + (((kb8 + 1) ^ (vdh & 7)) << 3)) = v1;
  };

  const int nkt  = qb + 1;
  const int qrow = qb * 64 + wid * 16;

  // ---- Q B-fragments (scale*log2e folded, pkrtz) ----
  f16x8 bq[2];
  {
    const float* qp = qbase + (size_t)(qrow + n) * D_ + g * 8;
    float x[16];
#pragma unroll
    for (int c = 0; c < 2; ++c) {
      *(float4*)(x + 8*c)     = *(const float4*)(qp + c * 32);
      *(float4*)(x + 8*c + 4) = *(const float4*)(qp + c * 32 + 4);
    }
    bq[0] = cvt8(x, SCALE_LOG2);
    bq[1] = cvt8(x + 8, SCALE_LOG2);
  }

  f32x4 o_acc[4] = {};
  float m_run = 0.f, l_run = 0.f;   // m=0 start: speculative exp2 never sees +inf

  load_tile(0);

  for (int kt = 0; kt < nkt; ++kt) {
    __syncthreads();              // previous compute done; LDS free
    store_tile();
    __syncthreads();
    if (kt + 1 < nkt) load_tile(kt + 1);   // issue early; hides under compute

    __builtin_amdgcn_s_setprio(1);
    // ---- QK^T ----
    const char* kb_ = (const char*)lds_k;
    f32x4 sc[4] = {};
#pragma unroll
    for (int t = 0; t < 4; ++t) {
      int keyl = t * 16 + n;
#pragma unroll
      for (int c = 0; c < 2; ++c) {
        int off = keyl * 128 + (((c * 4 + g) ^ (keyl & 7)) << 4);
        f16x8 ak = *(f16x8*)(kb_ + off);
        sc[t] = __builtin_amdgcn_mfma_f32_16x16x32_f16(ak, bq[c], sc[t], 0, 0, 0);
      }
    }

    // ---- causal mask: last tile only ----
    if (kt == nkt - 1) {
      int q = qrow + n;
#pragma unroll
      for (int t = 0; t < 4; ++t)
#pragma unroll
        for (int r = 0; r < 4; ++r) {
          int key = kt * KB + t * 16 + 4 * g + r;
          if (key > q) sc[t][r] = -1e30f;
        }
    }

    // ---- speculative softmax (defer-max) ----
    float mxt[4];
#pragma unroll
    for (int t = 0; t < 4; ++t)
      mxt[t] = fmaxf(fmaxf(sc[t][0], sc[t][1]), fmaxf(sc[t][2], sc[t][3]));
    float mx = fmaxf(fmaxf(mxt[0], mxt[1]), fmaxf(mxt[2], mxt[3]));
    mx = fmaxf(mx, __shfl_xor(mx, 16, 64));
    mx = fmaxf(mx, __shfl_xor(mx, 32, 64));

    float s = 0.f;
#pragma unroll
    for (int t = 0; t < 4; ++t) {
      f32x4 p = sc[t];
#pragma unroll
      for (int r = 0; r < 4; ++r) p[r] = exp2f(p[r] - m_run);
      sc[t] = p;
      s += (p[0] + p[1]) + (p[2] + p[3]);
    }

    if (!__all(mx <= m_run + THR)) {        // rare exact-rescale path
      float mnew  = fmaxf(m_run, mx);
      float alpha = exp2f(m_run - mnew);
#pragma unroll
      for (int t = 0; t < 4; ++t)
#pragma unroll
        for (int r = 0; r < 4; ++r) sc[t][r] *= alpha;
      s *= alpha;
      l_run *= alpha;
      m_run = mnew;
      float ar[4];
#pragma unroll
      for (int r = 0; r < 4; ++r) ar[r] = __shfl(alpha, 4 * g + r, 64);
#pragma unroll
      for (int nt = 0; nt < 4; ++nt)
#pragma unroll
        for (int r = 0; r < 4; ++r) o_acc[nt][r] *= ar[r];
    }
    l_run += s;

    // ---- P fragments (lane-local, pkrtz) ----
    f16x4 pa[4];
#pragma unroll
    for (int u = 0; u < 4; ++u) {
      h16x2 p0 = __builtin_amdgcn_cvt_pkrtz(sc[u][0], sc[u][1]);
      h16x2 p1 = __builtin_amdgcn_cvt_pkrtz(sc[u][2], sc[u][3]);
      f16x4 p4;
      p4[0] = (_Float16)p0[0]; p4[1] = (_Float16)p0[1];
      p4[2] = (_Float16)p1[0]; p4[3] = (_Float16)p1[1];
      pa[u] = p4;
    }

    // ---- PV ----
#pragma unroll
    for (int u = 0; u < 4; ++u) {
#pragma unroll
      for (int nt = 0; nt < 4; ++nt) {
        int dhv = nt * 16 + n;
        int off = dhv * 64 + ((((2 * u + (g >> 1)) ^ (n & 7))) << 3) + ((g & 1) << 2);
        f16x4 bv = *(f16x4*)(lds_v + off);
        o_acc[nt] = __builtin_amdgcn_mfma_f32_16x16x16f16(pa[u], bv, o_acc[nt], 0, 0, 0);
      }
    }
    __builtin_amdgcn_s_setprio(0);
  } // kt

  // ---- epilogue ----
  float lsum = l_run;
  lsum += __shfl_xor(lsum, 16, 64);
  lsum += __shfl_xor(lsum, 32, 64);
  float linv[4];
#pragma unroll
  for (int r = 0; r < 4; ++r) linv[r] = 1.0f / __shfl(lsum, 4 * g + r, 64);

  float* ob = out + ((size_t)b * S_ + qrow) * D_ + h * DH;
#pragma unroll
  for (int r = 0; r < 4; ++r) {
    float* op = ob + (size_t)(4 * g + r) * D_ + n;
#pragma unroll
    for (int nt = 0; nt < 4; ++nt)
      op[nt * 16] = o_acc[nt][r] * linv[r];
  }
}

extern "C" void kernel_launch(void* const* d_in, const int* in_sizes, int n_in,
                              void* d_out, int out_size, void* d_ws, size_t ws_size,
                              hipStream_t stream) {
  const float* q = (const float*)d_in[0];
  const float* k = (const float*)d_in[1];
  const float* v = (const float*)d_in[2];
  // d_in[3]: causal mask (tril by construction) — handled analytically.
  float* out = (float*)d_out;
  dim3 grid(1024);   // one 64-row q-tile per block, LPT-ordered, XCD-local bh
  mha_fwd<<<grid, 256, 0, stream>>>(q, k, v, out);
}